// Round 4
// baseline (16519.510 us; speedup 1.0000x reference)
//
#include <hip/hip_runtime.h>

// spk_vector (B=4, S=2, D=512, T=16000) f32; x[b,t,s,:] = in[b][s][:][t].
// Output (B, C=2, D, T). 100 iterations of per-frame 2-means.
//
// Per-frame state: x = A * [v0; v1], A one of:
//  0: [[1,0],[0,1]]  1: [[0,1],[1,0]]  2: [[1,1],[0,0]]  3: [[0,0],[1,1]]
// Transition from per-row assignments (i0,i1):
//  (0,0)->2  (1,1)->3  (0,1)->keep  (1,0)->st^1
#define NB 4
#define ND 512
#define NT 16000
#define NITERS 100
#define BLK 256
#define TBLK 63   // ceil(16000/256)

static_assert(BLK % 64 == 0, "block must be waves");

// All scratch in static device globals (~1.9 MB) — no d_ws dependence,
// everything re-initialized by init_kernel on every call (graph-replay safe).
__device__ unsigned char g_states[NB * NT];
__device__ float g_n00[NB * NT];
__device__ float g_n11[NB * NT];
__device__ float g_nsum[NB * NT];
__device__ float g_partial[(size_t)NB * TBLK * 2 * ND];
__device__ int g_changed[NITERS + 1];

__global__ __launch_bounds__(BLK) void init_kernel(const float* __restrict__ in) {
  int b = blockIdx.y, blk = blockIdx.x, tid = threadIdx.x;
  int t = blk * BLK + tid;
  bool act = t < NT;
  int tc = act ? t : 0;
  float msk = act ? 1.f : 0.f;
  int wave = tid >> 6, lane = tid & 63;
  const float* p0 = in + ((size_t)(b * 2 + 0)) * ND * NT + tc;
  const float* p1 = in + ((size_t)(b * 2 + 1)) * ND * NT + tc;
  __shared__ float accw[4][2][ND];
  float a00 = 0.f, a11 = 0.f, as = 0.f;
#pragma unroll 4
  for (int d = 0; d < ND; ++d) {
    float v0 = msk * p0[(size_t)d * NT];
    float v1 = msk * p1[(size_t)d * NT];
    a00 += v0 * v0;
    a11 += v1 * v1;
    float s = v0 + v1;
    as += s * s;
    float r0 = v0, r1 = v1;
#pragma unroll
    for (int m = 1; m < 64; m <<= 1) {
      r0 += __shfl_xor(r0, m);
      r1 += __shfl_xor(r1, m);
    }
    if (lane == 0) { accw[wave][0][d] = r0; accw[wave][1][d] = r1; }
  }
  __syncthreads();
  for (int i = tid; i < 2 * ND; i += BLK) {
    int c = i / ND, d = i % ND;
    g_partial[((size_t)(b * TBLK + blk)) * (2 * ND) + i] =
        accw[0][c][d] + accw[1][c][d] + accw[2][c][d] + accw[3][c][d];
  }
  if (act) {
    size_t f = (size_t)b * NT + t;
    g_n00[f] = a00; g_n11[f] = a11; g_nsum[f] = as;
    g_states[f] = 0;
  }
  if (b == 0 && blk == 0) {
    for (int i = tid; i <= NITERS; i += BLK) g_changed[i] = (i == 0) ? 1 : 0;
  }
}

__global__ __launch_bounds__(BLK) void pass_kernel(const float* __restrict__ in,
                                                   int iter) {
  if (g_changed[iter] == 0) return;  // uniform: fixed point reached
  int b = blockIdx.y, blk = blockIdx.x, tid = threadIdx.x;
  int t = blk * BLK + tid;
  bool act = t < NT;
  int tc = act ? t : 0;
  float msk = act ? 1.f : 0.f;
  int wave = tid >> 6, lane = tid & 63;
  __shared__ float cl[2 * ND];
  __shared__ float c2s[2];
  __shared__ float accw[4][2][ND];
  // Rebuild centroids from previous pass's partials: fixed chain order,
  // identical inputs in every block -> bit-identical results everywhere.
  for (int i = tid; i < 2 * ND; i += BLK) {
    float s = 0.f;
    for (int p = 0; p < TBLK; ++p)
      s += g_partial[((size_t)(b * TBLK + p)) * (2 * ND) + i];
    cl[i] = s / (float)NT;   // true divide, matches np.mean
  }
  __syncthreads();
  if (tid < 64) {  // wave 0: c2 = ||cent||^2, fixed deterministic order
    float q0 = 0.f, q1 = 0.f;
    for (int d = lane; d < ND; d += 64) {
      float a = cl[d], e = cl[ND + d];
      q0 += a * a; q1 += e * e;
    }
#pragma unroll
    for (int m = 1; m < 64; m <<= 1) {
      q0 += __shfl_xor(q0, m);
      q1 += __shfl_xor(q1, m);
    }
    if (lane == 0) { c2s[0] = q0; c2s[1] = q1; }
  }
  __syncthreads();
  const float* p0 = in + ((size_t)(b * 2 + 0)) * ND * NT + tc;
  const float* p1 = in + ((size_t)(b * 2 + 1)) * ND * NT + tc;
  // phase 1: dots of v0,v1 with both centroids
  float g00 = 0.f, g01 = 0.f, g10 = 0.f, g11 = 0.f;
#pragma unroll 8
  for (int d = 0; d < ND; ++d) {
    float v0 = msk * p0[(size_t)d * NT];
    float v1 = msk * p1[(size_t)d * NT];
    float c0 = cl[d], c1 = cl[ND + d];
    g00 += v0 * c0; g01 += v0 * c1;
    g10 += v1 * c0; g11 += v1 * c1;
  }
  size_t f = (size_t)b * NT + (size_t)tc;
  unsigned char st_old = (unsigned char)(g_states[f] & 3);
  float a00 = msk * g_n00[f], a11 = msk * g_n11[f], asum = msk * g_nsum[f];
  float x2_0, x2_1, d00, d01, d10, d11;
  switch (st_old) {
    case 0: x2_0 = a00;  x2_1 = a11;  d00 = g00;       d01 = g01;       d10 = g10;       d11 = g11;       break;
    case 1: x2_0 = a11;  x2_1 = a00;  d00 = g10;       d01 = g11;       d10 = g00;       d11 = g01;       break;
    case 2: x2_0 = asum; x2_1 = 0.f;  d00 = g00 + g10; d01 = g01 + g11; d10 = 0.f;       d11 = 0.f;       break;
    default: x2_0 = 0.f; x2_1 = asum; d00 = 0.f;       d01 = 0.f;       d10 = g00 + g10; d11 = g01 + g11; break;
  }
  float c2_0 = c2s[0], c2_1 = c2s[1];
  // replicate ref rounding: fl(fl(x2+c2) - 2*dot); 2*dot exact
  float dist00 = (x2_0 + c2_0) - 2.f * d00;
  float dist01 = (x2_0 + c2_1) - 2.f * d01;
  float dist10 = (x2_1 + c2_0) - 2.f * d10;
  float dist11 = (x2_1 + c2_1) - 2.f * d11;
  int i0 = (dist00 <= dist01) ? 0 : 1;   // argmin tie -> 0 (np first-min)
  int i1 = (dist10 <= dist11) ? 0 : 1;
  unsigned char st_new;
  if (i0 == 0 && i1 == 0) st_new = 2;
  else if (i0 == 1 && i1 == 1) st_new = 3;
  else if (i0 == 0) st_new = st_old;
  else st_new = (unsigned char)(st_old ^ 1);
  if (act) {
    g_states[f] = st_new;
    if (st_new != st_old) g_changed[iter + 1] = 1;  // benign same-value race
  }
  // phase 2: accumulate new cluster sums (deterministic lane tree)
  bool w0 = (st_new == 0 || st_new == 2);  // v0 -> cluster 0
  bool w1 = (st_new == 1 || st_new == 2);  // v1 -> cluster 0
#pragma unroll 4
  for (int d = 0; d < ND; ++d) {
    float v0 = msk * p0[(size_t)d * NT];
    float v1 = msk * p1[(size_t)d * NT];
    float a0 = (w0 ? v0 : 0.f) + (w1 ? v1 : 0.f);
    float a1 = (w0 ? 0.f : v0) + (w1 ? 0.f : v1);
#pragma unroll
    for (int m = 1; m < 64; m <<= 1) {
      a0 += __shfl_xor(a0, m);
      a1 += __shfl_xor(a1, m);
    }
    if (lane == 0) { accw[wave][0][d] = a0; accw[wave][1][d] = a1; }
  }
  __syncthreads();
  for (int i = tid; i < 2 * ND; i += BLK) {
    int c = i / ND, d = i % ND;
    g_partial[((size_t)(b * TBLK + blk)) * (2 * ND) + i] =
        accw[0][c][d] + accw[1][c][d] + accw[2][c][d] + accw[3][c][d];
  }
}

__global__ __launch_bounds__(BLK) void output_kernel(const float* __restrict__ in,
                                                     float* __restrict__ out) {
  int b = blockIdx.y, blk = blockIdx.x;
  int t = blk * BLK + (int)threadIdx.x;
  if (t >= NT) return;
  unsigned char st = (unsigned char)(g_states[(size_t)b * NT + t] & 3);
  const float* p0 = in + ((size_t)(b * 2 + 0)) * ND * NT + t;
  const float* p1 = in + ((size_t)(b * 2 + 1)) * ND * NT + t;
  float* o0 = out + ((size_t)(b * 2 + 0)) * ND * NT + t;
  float* o1 = out + ((size_t)(b * 2 + 1)) * ND * NT + t;
  bool w0 = (st == 0 || st == 2), w1 = (st == 1 || st == 2);
#pragma unroll 4
  for (int d = 0; d < ND; ++d) {
    float v0 = p0[(size_t)d * NT], v1 = p1[(size_t)d * NT];
    float a0 = (w0 ? v0 : 0.f) + (w1 ? v1 : 0.f);  // exact: 0, v, or fl(v0+v1)
    float a1 = (w0 ? 0.f : v0) + (w1 ? 0.f : v1);
    o0[(size_t)d * NT] = a0;
    o1[(size_t)d * NT] = a1;
  }
}

extern "C" void kernel_launch(void* const* d_in, const int* in_sizes, int n_in,
                              void* d_out, int out_size, void* d_ws, size_t ws_size,
                              hipStream_t stream) {
  const float* in = (const float*)d_in[0];
  float* out = (float*)d_out;
  (void)d_ws; (void)ws_size; (void)in_sizes; (void)n_in; (void)out_size;

  dim3 grid(TBLK, NB), blk(BLK);
  init_kernel<<<grid, blk, 0, stream>>>(in);
  for (int i = 0; i < NITERS; ++i)
    pass_kernel<<<grid, blk, 0, stream>>>(in, i);
  output_kernel<<<grid, blk, 0, stream>>>(in, out);
}

// Round 6
// 5320.421 us; speedup vs baseline: 3.1049x; 3.1049x over previous
//
#include <hip/hip_runtime.h>

// spk_vector (B=4, S=2, D=512, T=16000) f32; x[b,t,s,:] = in[b][s][:][t].
// Output (B, C=2, D, T). 100 iterations of per-frame 2-means.
//
// Per-frame state: x = A * [v0; v1], A one of:
//  0: [[1,0],[0,1]]  1: [[0,1],[1,0]]  2: [[1,1],[0,0]]  3: [[0,0],[1,1]]
// Transition from per-row assignments (i0,i1):
//  (0,0)->2  (1,1)->3  (0,1)->keep  (1,0)->st^1
#define NB 4
#define ND 512
#define NT 16000
#define NITERS 100
#define DS 8      // d-chunks of 64
#define DCH 64
#define TCH 16    // t-chunks of 1000 frames
#define FPC 1000
#define FPT 4     // frames per thread (float4)
#define APT 250   // active threads per block

// Static device scratch (~18 MB) — no d_ws dependence; fully re-initialized
// by init kernels each call (graph-replay safe).
__device__ __align__(16) unsigned char g_states[NB * NT];
__device__ float4 g_nfin[NB * NT];       // (n00, n11, nsum, 0) per frame
__device__ float4 g_npart[NB * DS * NT]; // init partials per d-chunk
__device__ float4 g_pdot[NB * DS * NT];  // (g00,g01,g10,g11) partial dots
__device__ float g_Spart[NB * DS * TCH * 2 * DCH];  // cluster-sum partials
__device__ int g_changed[NITERS + 1];

__device__ __forceinline__ float4 ld4(const float* p) { return *(const float4*)p; }

#define WREDUCE2(a0, a1)                     \
  _Pragma("unroll")                          \
  for (int m = 1; m < 64; m <<= 1) {         \
    a0 += __shfl_xor(a0, m);                 \
    a1 += __shfl_xor(a1, m);                 \
  }

#define MKW(st_, w0_, w1_)                   \
  do { w0_ = (st_ == 0) || (st_ == 2);       \
       w1_ = (st_ == 1) || (st_ == 2); } while (0)

// ---- init: per-frame norms (chunk partials) + initial cluster partials ----
__global__ __launch_bounds__(256) void init_kernel(const float* __restrict__ in) {
  int j = blockIdx.x, tc = blockIdx.y, b = blockIdx.z, tid = threadIdx.x;
  int wave = tid >> 6, lane = tid & 63;
  bool act = tid < APT;
  int t0 = tc * FPC + tid * FPT;
  int t0c = act ? t0 : 0;
  float msk = act ? 1.f : 0.f;
  __shared__ float accw[4][2][DCH];
  const float* base0 = in + ((size_t)(b * 2 + 0) * ND) * NT;
  const float* base1 = in + ((size_t)(b * 2 + 1) * ND) * NT;
  float4 q00 = {0, 0, 0, 0}, q11 = {0, 0, 0, 0}, qs = {0, 0, 0, 0};
#pragma unroll 2
  for (int dl = 0; dl < DCH; ++dl) {
    int d = j * DCH + dl;
    float4 v0 = ld4(base0 + (size_t)d * NT + t0c);
    float4 v1 = ld4(base1 + (size_t)d * NT + t0c);
    v0.x *= msk; v0.y *= msk; v0.z *= msk; v0.w *= msk;
    v1.x *= msk; v1.y *= msk; v1.z *= msk; v1.w *= msk;
    q00.x = fmaf(v0.x, v0.x, q00.x); q00.y = fmaf(v0.y, v0.y, q00.y);
    q00.z = fmaf(v0.z, v0.z, q00.z); q00.w = fmaf(v0.w, v0.w, q00.w);
    q11.x = fmaf(v1.x, v1.x, q11.x); q11.y = fmaf(v1.y, v1.y, q11.y);
    q11.z = fmaf(v1.z, v1.z, q11.z); q11.w = fmaf(v1.w, v1.w, q11.w);
    float sx = v0.x + v1.x, sy = v0.y + v1.y, sz = v0.z + v1.z, sw = v0.w + v1.w;
    qs.x = fmaf(sx, sx, qs.x); qs.y = fmaf(sy, sy, qs.y);
    qs.z = fmaf(sz, sz, qs.z); qs.w = fmaf(sw, sw, qs.w);
    // initial states are all 0: cluster0 sum = sum v0, cluster1 sum = sum v1
    float a0 = (v0.x + v0.y) + (v0.z + v0.w);
    float a1 = (v1.x + v1.y) + (v1.z + v1.w);
    WREDUCE2(a0, a1)
    if (lane == 0) { accw[wave][0][dl] = a0; accw[wave][1][dl] = a1; }
  }
  __syncthreads();
  if (tid < 2 * DCH) {
    int c = tid >> 6, dl = tid & 63;
    g_Spart[(((size_t)(b * DS + j) * TCH + tc) * 2 + c) * DCH + dl] =
        ((accw[0][c][dl] + accw[1][c][dl]) + accw[2][c][dl]) + accw[3][c][dl];
  }
  if (act) {
    size_t pb = (size_t)(b * DS + j) * NT + t0;
    g_npart[pb + 0] = make_float4(q00.x, q11.x, qs.x, 0.f);
    g_npart[pb + 1] = make_float4(q00.y, q11.y, qs.y, 0.f);
    g_npart[pb + 2] = make_float4(q00.z, q11.z, qs.z, 0.f);
    g_npart[pb + 3] = make_float4(q00.w, q11.w, qs.w, 0.f);
  }
  if (j == 0 && act) *(uchar4*)&g_states[(size_t)b * NT + t0] = make_uchar4(0, 0, 0, 0);
  if (j == 0 && tc == 0 && b == 0)
    for (int i = tid; i <= NITERS; i += 256) g_changed[i] = (i == 0) ? 1 : 0;
}

// ---- init2: reduce norm partials over d-chunks (j ascending) ----
__global__ __launch_bounds__(256) void init2_kernel() {
  int blk = blockIdx.x, b = blockIdx.y;
  int t = blk * 256 + (int)threadIdx.x;
  if (t >= NT) return;
  float n00 = 0.f, n11 = 0.f, ns = 0.f;
  for (int jj = 0; jj < DS; ++jj) {
    float4 p = g_npart[(size_t)(b * DS + jj) * NT + t];
    n00 += p.x; n11 += p.y; ns += p.z;
  }
  g_nfin[(size_t)b * NT + t] = make_float4(n00, n11, ns, 0.f);
}

// ---- A: partial dots of v0,v1 with both centroids over one d-chunk ----
__global__ __launch_bounds__(256) void dots_kernel(const float* __restrict__ in, int iter) {
  if (g_changed[iter] == 0) return;  // uniform early-out after convergence
  int j = blockIdx.x, tc = blockIdx.y, b = blockIdx.z, tid = threadIdx.x;
  __shared__ float cl[2][DCH];
  if (tid < 2 * DCH) {  // rebuild cent chunk, tc-ascending fixed order
    int c = tid >> 6, dl = tid & 63;
    float s = 0.f;
    for (int p = 0; p < TCH; ++p)
      s += g_Spart[(((size_t)(b * DS + j) * TCH + p) * 2 + c) * DCH + dl];
    cl[c][dl] = s / (float)NT;
  }
  __syncthreads();
  bool act = tid < APT;
  int t0 = tc * FPC + tid * FPT;
  int t0c = act ? t0 : 0;
  const float* base0 = in + ((size_t)(b * 2 + 0) * ND) * NT;
  const float* base1 = in + ((size_t)(b * 2 + 1) * ND) * NT;
  float4 g00 = {0,0,0,0}, g01 = {0,0,0,0}, g10 = {0,0,0,0}, g11 = {0,0,0,0};
#pragma unroll 4
  for (int dl = 0; dl < DCH; ++dl) {
    int d = j * DCH + dl;
    float4 v0 = ld4(base0 + (size_t)d * NT + t0c);
    float4 v1 = ld4(base1 + (size_t)d * NT + t0c);
    float c0 = cl[0][dl], c1 = cl[1][dl];
    g00.x = fmaf(v0.x, c0, g00.x); g00.y = fmaf(v0.y, c0, g00.y);
    g00.z = fmaf(v0.z, c0, g00.z); g00.w = fmaf(v0.w, c0, g00.w);
    g01.x = fmaf(v0.x, c1, g01.x); g01.y = fmaf(v0.y, c1, g01.y);
    g01.z = fmaf(v0.z, c1, g01.z); g01.w = fmaf(v0.w, c1, g01.w);
    g10.x = fmaf(v1.x, c0, g10.x); g10.y = fmaf(v1.y, c0, g10.y);
    g10.z = fmaf(v1.z, c0, g10.z); g10.w = fmaf(v1.w, c0, g10.w);
    g11.x = fmaf(v1.x, c1, g11.x); g11.y = fmaf(v1.y, c1, g11.y);
    g11.z = fmaf(v1.z, c1, g11.z); g11.w = fmaf(v1.w, c1, g11.w);
  }
  if (act) {
    size_t pb = (size_t)(b * DS + j) * NT + t0;
    g_pdot[pb + 0] = make_float4(g00.x, g01.x, g10.x, g11.x);
    g_pdot[pb + 1] = make_float4(g00.y, g01.y, g10.y, g11.y);
    g_pdot[pb + 2] = make_float4(g00.z, g01.z, g10.z, g11.z);
    g_pdot[pb + 3] = make_float4(g00.w, g01.w, g10.w, g11.w);
  }
}

// ---- B: per-frame assignment + state transition + convergence flag ----
__global__ __launch_bounds__(256) void upd_kernel(int iter) {
  if (g_changed[iter] == 0) return;
  int blk = blockIdx.x, b = blockIdx.y, tid = threadIdx.x;
  __shared__ float clf[2 * ND];
  __shared__ float c2s[2];
  for (int i = tid; i < 2 * ND; i += 256) {  // same tc-ascending rebuild bits
    int c = i >> 9, d = i & 511;
    int jj = d >> 6, dl = d & 63;
    float s = 0.f;
    for (int p = 0; p < TCH; ++p)
      s += g_Spart[(((size_t)(b * DS + jj) * TCH + p) * 2 + c) * DCH + dl];
    clf[i] = s / (float)NT;
  }
  __syncthreads();
  int lane = tid & 63;
  if (tid < 64) {  // c2 = ||cent||^2, same order as round-4 (passed)
    float q0 = 0.f, q1 = 0.f;
    for (int d = lane; d < ND; d += 64) {
      float a = clf[d], e = clf[ND + d];
      q0 += a * a; q1 += e * e;
    }
    WREDUCE2(q0, q1)
    if (lane == 0) { c2s[0] = q0; c2s[1] = q1; }
  }
  __syncthreads();
  int t = blk * 256 + tid;
  if (t >= NT) return;
  size_t f = (size_t)b * NT + t;
  float g00 = 0.f, g01 = 0.f, g10 = 0.f, g11 = 0.f;
  for (int jj = 0; jj < DS; ++jj) {  // j-ascending fixed order
    float4 p = g_pdot[(size_t)(b * DS + jj) * NT + t];
    g00 += p.x; g01 += p.y; g10 += p.z; g11 += p.w;
  }
  float4 nf = g_nfin[f];
  float a00 = nf.x, a11 = nf.y, asum = nf.z;
  unsigned char st_old = (unsigned char)(g_states[f] & 3);
  float x2_0, x2_1, d00, d01, d10, d11;
  switch (st_old) {
    case 0: x2_0 = a00;  x2_1 = a11;  d00 = g00;       d01 = g01;       d10 = g10;       d11 = g11;       break;
    case 1: x2_0 = a11;  x2_1 = a00;  d00 = g10;       d01 = g11;       d10 = g00;       d11 = g01;       break;
    case 2: x2_0 = asum; x2_1 = 0.f;  d00 = g00 + g10; d01 = g01 + g11; d10 = 0.f;       d11 = 0.f;       break;
    default: x2_0 = 0.f; x2_1 = asum; d00 = 0.f;       d01 = 0.f;       d10 = g00 + g10; d11 = g01 + g11; break;
  }
  float c2_0 = c2s[0], c2_1 = c2s[1];
  float dist00 = (x2_0 + c2_0) - 2.f * d00;
  float dist01 = (x2_0 + c2_1) - 2.f * d01;
  float dist10 = (x2_1 + c2_0) - 2.f * d10;
  float dist11 = (x2_1 + c2_1) - 2.f * d11;
  int i0 = (dist00 <= dist01) ? 0 : 1;   // argmin tie -> 0 (np first-min)
  int i1 = (dist10 <= dist11) ? 0 : 1;
  unsigned char st_new;
  if (i0 == 0 && i1 == 0) st_new = 2;
  else if (i0 == 1 && i1 == 1) st_new = 3;
  else if (i0 == 0) st_new = st_old;
  else st_new = (unsigned char)(st_old ^ 1);
  g_states[f] = st_new;
  if (st_new != st_old) g_changed[iter + 1] = 1;  // benign same-value race
}

// ---- C: cluster-sum partials for next iteration (skipped if no change) ----
__global__ __launch_bounds__(256) void csum_kernel(const float* __restrict__ in, int iter) {
  if (g_changed[iter + 1] == 0) return;  // states identical => Spart already valid
  int j = blockIdx.x, tc = blockIdx.y, b = blockIdx.z, tid = threadIdx.x;
  int wave = tid >> 6, lane = tid & 63;
  bool act = tid < APT;
  int t0 = tc * FPC + tid * FPT;
  int t0c = act ? t0 : 0;
  float msk = act ? 1.f : 0.f;
  __shared__ float accw[4][2][DCH];
  uchar4 st = *(const uchar4*)&g_states[(size_t)b * NT + t0c];
  bool w00, w10, w01, w11, w02, w12, w03, w13;
  MKW(st.x, w00, w10); MKW(st.y, w01, w11); MKW(st.z, w02, w12); MKW(st.w, w03, w13);
  const float* base0 = in + ((size_t)(b * 2 + 0) * ND) * NT;
  const float* base1 = in + ((size_t)(b * 2 + 1) * ND) * NT;
#pragma unroll 2
  for (int dl = 0; dl < DCH; ++dl) {
    int d = j * DCH + dl;
    float4 v0 = ld4(base0 + (size_t)d * NT + t0c);
    float4 v1 = ld4(base1 + (size_t)d * NT + t0c);
    v0.x *= msk; v0.y *= msk; v0.z *= msk; v0.w *= msk;
    v1.x *= msk; v1.y *= msk; v1.z *= msk; v1.w *= msk;
    float p0x = (w00 ? v0.x : 0.f) + (w10 ? v1.x : 0.f);
    float p1x = (w00 ? 0.f : v0.x) + (w10 ? 0.f : v1.x);
    float p0y = (w01 ? v0.y : 0.f) + (w11 ? v1.y : 0.f);
    float p1y = (w01 ? 0.f : v0.y) + (w11 ? 0.f : v1.y);
    float p0z = (w02 ? v0.z : 0.f) + (w12 ? v1.z : 0.f);
    float p1z = (w02 ? 0.f : v0.z) + (w12 ? 0.f : v1.z);
    float p0w = (w03 ? v0.w : 0.f) + (w13 ? v1.w : 0.f);
    float p1w = (w03 ? 0.f : v0.w) + (w13 ? 0.f : v1.w);
    float a0 = (p0x + p0y) + (p0z + p0w);
    float a1 = (p1x + p1y) + (p1z + p1w);
    WREDUCE2(a0, a1)
    if (lane == 0) { accw[wave][0][dl] = a0; accw[wave][1][dl] = a1; }
  }
  __syncthreads();
  if (tid < 2 * DCH) {
    int c = tid >> 6, dl = tid & 63;
    g_Spart[(((size_t)(b * DS + j) * TCH + tc) * 2 + c) * DCH + dl] =
        ((accw[0][c][dl] + accw[1][c][dl]) + accw[2][c][dl]) + accw[3][c][dl];
  }
}

// ---- output: exact select/add of original vectors per final state ----
__global__ __launch_bounds__(256) void output_kernel(const float* __restrict__ in,
                                                     float* __restrict__ out) {
  int j = blockIdx.x, tc = blockIdx.y, b = blockIdx.z, tid = threadIdx.x;
  if (tid >= APT) return;
  int t0 = tc * FPC + tid * FPT;
  uchar4 st = *(const uchar4*)&g_states[(size_t)b * NT + t0];
  bool w00, w10, w01, w11, w02, w12, w03, w13;
  MKW(st.x, w00, w10); MKW(st.y, w01, w11); MKW(st.z, w02, w12); MKW(st.w, w03, w13);
  const float* b0 = in + ((size_t)(b * 2 + 0) * ND) * NT;
  const float* b1 = in + ((size_t)(b * 2 + 1) * ND) * NT;
  float* o0 = out + ((size_t)(b * 2 + 0) * ND) * NT;
  float* o1 = out + ((size_t)(b * 2 + 1) * ND) * NT;
#pragma unroll 2
  for (int dl = 0; dl < DCH; ++dl) {
    int d = j * DCH + dl;
    float4 v0 = ld4(b0 + (size_t)d * NT + t0);
    float4 v1 = ld4(b1 + (size_t)d * NT + t0);
    float4 a0, a1;
    a0.x = (w00 ? v0.x : 0.f) + (w10 ? v1.x : 0.f);
    a1.x = (w00 ? 0.f : v0.x) + (w10 ? 0.f : v1.x);
    a0.y = (w01 ? v0.y : 0.f) + (w11 ? v1.y : 0.f);
    a1.y = (w01 ? 0.f : v0.y) + (w11 ? 0.f : v1.y);
    a0.z = (w02 ? v0.z : 0.f) + (w12 ? v1.z : 0.f);
    a1.z = (w02 ? 0.f : v0.z) + (w12 ? 0.f : v1.z);
    a0.w = (w03 ? v0.w : 0.f) + (w13 ? v1.w : 0.f);
    a1.w = (w03 ? 0.f : v0.w) + (w13 ? 0.f : v1.w);
    *(float4*)(o0 + (size_t)d * NT + t0) = a0;
    *(float4*)(o1 + (size_t)d * NT + t0) = a1;
  }
}

extern "C" void kernel_launch(void* const* d_in, const int* in_sizes, int n_in,
                              void* d_out, int out_size, void* d_ws, size_t ws_size,
                              hipStream_t stream) {
  const float* in = (const float*)d_in[0];
  float* out = (float*)d_out;
  (void)d_ws; (void)ws_size; (void)in_sizes; (void)n_in; (void)out_size;

  dim3 g3(DS, TCH, NB), b256(256);
  init_kernel<<<g3, b256, 0, stream>>>(in);
  init2_kernel<<<dim3(63, NB), b256, 0, stream>>>();
  for (int i = 0; i < NITERS; ++i) {
    dots_kernel<<<g3, b256, 0, stream>>>(in, i);
    upd_kernel<<<dim3(63, NB), b256, 0, stream>>>(i);
    if (i < NITERS - 1) csum_kernel<<<g3, b256, 0, stream>>>(in, i);
  }
  output_kernel<<<g3, b256, 0, stream>>>(in, out);
}

// Round 7
// 4562.480 us; speedup vs baseline: 3.6207x; 1.1661x over previous
//
#include <hip/hip_runtime.h>

// spk_vector (B=4, S=2, D=512, T=16000) f32; x[b,t,s,:] = in[b][s][:][t].
// Output (B, C=2, D, T). 100 iterations of per-frame 2-means.
//
// Per-frame state: x = A * [v0; v1], A one of:
//  0: [[1,0],[0,1]]  1: [[0,1],[1,0]]  2: [[1,1],[0,0]]  3: [[0,0],[1,1]]
// Transition from per-row assignments (i0,i1):
//  (0,0)->2  (1,1)->3  (0,1)->keep  (1,0)->st^1
#define NB 4
#define ND 512
#define NT 16000
#define NITERS 100
#define DS 8      // d-chunks of 64
#define DCH 64
#define TCH 16    // t-chunks of 1000 frames
#define FPC 1000
#define FPT 4     // frames per thread (float4)
#define APT 250   // active threads per block
#define NWCH 64   // wave-chunks per batch: TCH * 4 waves (256-frame granules)

// Static device scratch (~19 MB) — no d_ws dependence; fully re-initialized
// by init kernels each call (graph-replay safe).
__device__ __align__(16) unsigned char g_states[NB * NT];
__device__ float4 g_nfin[NB * NT];       // (n00, n11, nsum, 0) per frame
__device__ float4 g_npart[NB * DS * NT]; // init partials per d-chunk
__device__ float4 g_pdot[NB * DS * NT];  // (g00,g01,g10,g11) partial dots
// cluster-sum sub-partials at wave granularity: [b][j][p=tc*4+w][c][dl]
__device__ float g_Spart[(size_t)NB * DS * NWCH * 2 * DCH];
__device__ unsigned char g_chflag[(size_t)(NITERS + 1) * NB * NWCH];
__device__ int g_changed[NITERS + 1];

__device__ __forceinline__ float4 ld4(const float* p) { return *(const float4*)p; }

__device__ __forceinline__ size_t SP(int b, int j, int p, int c, int dl) {
  return (((size_t)(b * DS + j) * NWCH + p) * 2 + c) * DCH + dl;
}

#define WREDUCE2(a0, a1)                     \
  _Pragma("unroll")                          \
  for (int m = 1; m < 64; m <<= 1) {         \
    a0 += __shfl_xor(a0, m);                 \
    a1 += __shfl_xor(a1, m);                 \
  }

#define MKW(st_, w0_, w1_)                   \
  do { w0_ = (st_ == 0) || (st_ == 2);       \
       w1_ = (st_ == 1) || (st_ == 2); } while (0)

// ---- init: per-frame norm partials + initial cluster sub-partials ----
// Barrier-free: per-wave lane-keep reduction, wave w writes its own partial.
__global__ __launch_bounds__(256) void init_kernel(const float* __restrict__ in) {
  int j = blockIdx.x, tc = blockIdx.y, b = blockIdx.z, tid = threadIdx.x;
  int wave = tid >> 6, lane = tid & 63;
  bool act = tid < APT;
  int t0 = tc * FPC + tid * FPT;
  int t0c = act ? t0 : 0;
  float msk = act ? 1.f : 0.f;
  const float* base0 = in + ((size_t)(b * 2 + 0) * ND) * NT;
  const float* base1 = in + ((size_t)(b * 2 + 1) * ND) * NT;
  float4 q00 = {0, 0, 0, 0}, q11 = {0, 0, 0, 0}, qs = {0, 0, 0, 0};
  float r0 = 0.f, r1 = 0.f;   // lane-keep: dim sums for dl == lane
#pragma unroll 2
  for (int dl = 0; dl < DCH; ++dl) {
    int d = j * DCH + dl;
    float4 v0 = ld4(base0 + (size_t)d * NT + t0c);
    float4 v1 = ld4(base1 + (size_t)d * NT + t0c);
    v0.x *= msk; v0.y *= msk; v0.z *= msk; v0.w *= msk;
    v1.x *= msk; v1.y *= msk; v1.z *= msk; v1.w *= msk;
    q00.x = fmaf(v0.x, v0.x, q00.x); q00.y = fmaf(v0.y, v0.y, q00.y);
    q00.z = fmaf(v0.z, v0.z, q00.z); q00.w = fmaf(v0.w, v0.w, q00.w);
    q11.x = fmaf(v1.x, v1.x, q11.x); q11.y = fmaf(v1.y, v1.y, q11.y);
    q11.z = fmaf(v1.z, v1.z, q11.z); q11.w = fmaf(v1.w, v1.w, q11.w);
    float sx = v0.x + v1.x, sy = v0.y + v1.y, sz = v0.z + v1.z, sw = v0.w + v1.w;
    qs.x = fmaf(sx, sx, qs.x); qs.y = fmaf(sy, sy, qs.y);
    qs.z = fmaf(sz, sz, qs.z); qs.w = fmaf(sw, sw, qs.w);
    // initial states all 0: cluster0 sum = sum v0, cluster1 sum = sum v1
    float a0 = (v0.x + v0.y) + (v0.z + v0.w);
    float a1 = (v1.x + v1.y) + (v1.z + v1.w);
    WREDUCE2(a0, a1)
    if (lane == dl) { r0 = a0; r1 = a1; }
  }
  int p = tc * 4 + wave;
  g_Spart[SP(b, j, p, 0, lane)] = r0;
  g_Spart[SP(b, j, p, 1, lane)] = r1;
  if (act) {
    size_t pb = (size_t)(b * DS + j) * NT + t0;
    g_npart[pb + 0] = make_float4(q00.x, q11.x, qs.x, 0.f);
    g_npart[pb + 1] = make_float4(q00.y, q11.y, qs.y, 0.f);
    g_npart[pb + 2] = make_float4(q00.z, q11.z, qs.z, 0.f);
    g_npart[pb + 3] = make_float4(q00.w, q11.w, qs.w, 0.f);
  }
  if (j == 0 && act) *(uchar4*)&g_states[(size_t)b * NT + t0] = make_uchar4(0, 0, 0, 0);
  if (j == 0 && tc == 0 && b == 0) {
    for (int i = tid; i <= NITERS; i += 256) g_changed[i] = (i == 0) ? 1 : 0;
    for (size_t i = tid; i < (size_t)(NITERS + 1) * NB * NWCH; i += 256)
      g_chflag[i] = 0;
  }
}

// ---- init2: reduce norm partials over d-chunks (j ascending) ----
__global__ __launch_bounds__(256) void init2_kernel() {
  int blk = blockIdx.x, b = blockIdx.y;
  int t = blk * 256 + (int)threadIdx.x;
  if (t >= NT) return;
  float n00 = 0.f, n11 = 0.f, ns = 0.f;
  for (int jj = 0; jj < DS; ++jj) {
    float4 p = g_npart[(size_t)(b * DS + jj) * NT + t];
    n00 += p.x; n11 += p.y; ns += p.z;
  }
  g_nfin[(size_t)b * NT + t] = make_float4(n00, n11, ns, 0.f);
}

// ---- A: partial dots of v0,v1 with both centroids over one d-chunk ----
__global__ __launch_bounds__(256) void dots_kernel(const float* __restrict__ in, int iter) {
  if (g_changed[iter] == 0) return;  // uniform early-out after convergence
  int j = blockIdx.x, tc = blockIdx.y, b = blockIdx.z, tid = threadIdx.x;
  __shared__ float cl[2][DCH];
  if (tid < 2 * DCH) {  // rebuild cent chunk, p-ascending fixed order
    int c = tid >> 6, dl = tid & 63;
    float s = 0.f;
    for (int p = 0; p < NWCH; ++p) s += g_Spart[SP(b, j, p, c, dl)];
    cl[c][dl] = s / (float)NT;
  }
  __syncthreads();
  bool act = tid < APT;
  int t0 = tc * FPC + tid * FPT;
  int t0c = act ? t0 : 0;
  const float* base0 = in + ((size_t)(b * 2 + 0) * ND) * NT;
  const float* base1 = in + ((size_t)(b * 2 + 1) * ND) * NT;
  float4 g00 = {0,0,0,0}, g01 = {0,0,0,0}, g10 = {0,0,0,0}, g11 = {0,0,0,0};
#pragma unroll 4
  for (int dl = 0; dl < DCH; ++dl) {
    int d = j * DCH + dl;
    float4 v0 = ld4(base0 + (size_t)d * NT + t0c);
    float4 v1 = ld4(base1 + (size_t)d * NT + t0c);
    float c0 = cl[0][dl], c1 = cl[1][dl];
    g00.x = fmaf(v0.x, c0, g00.x); g00.y = fmaf(v0.y, c0, g00.y);
    g00.z = fmaf(v0.z, c0, g00.z); g00.w = fmaf(v0.w, c0, g00.w);
    g01.x = fmaf(v0.x, c1, g01.x); g01.y = fmaf(v0.y, c1, g01.y);
    g01.z = fmaf(v0.z, c1, g01.z); g01.w = fmaf(v0.w, c1, g01.w);
    g10.x = fmaf(v1.x, c0, g10.x); g10.y = fmaf(v1.y, c0, g10.y);
    g10.z = fmaf(v1.z, c0, g10.z); g10.w = fmaf(v1.w, c0, g10.w);
    g11.x = fmaf(v1.x, c1, g11.x); g11.y = fmaf(v1.y, c1, g11.y);
    g11.z = fmaf(v1.z, c1, g11.z); g11.w = fmaf(v1.w, c1, g11.w);
  }
  if (act) {
    size_t pb = (size_t)(b * DS + j) * NT + t0;
    g_pdot[pb + 0] = make_float4(g00.x, g01.x, g10.x, g11.x);
    g_pdot[pb + 1] = make_float4(g00.y, g01.y, g10.y, g11.y);
    g_pdot[pb + 2] = make_float4(g00.z, g01.z, g10.z, g11.z);
    g_pdot[pb + 3] = make_float4(g00.w, g01.w, g10.w, g11.w);
  }
}

// ---- B: per-frame assignment + state transition + dirty-chunk flags ----
__global__ __launch_bounds__(256) void upd_kernel(int iter) {
  if (g_changed[iter] == 0) return;
  int blk = blockIdx.x, b = blockIdx.y, tid = threadIdx.x;
  __shared__ float clf[2 * ND];
  __shared__ float c2s[2];
  for (int i = tid; i < 2 * ND; i += 256) {  // p-ascending rebuild, same bits
    int c = i >> 9, d = i & 511;
    int jj = d >> 6, dl = d & 63;
    float s = 0.f;
    for (int p = 0; p < NWCH; ++p) s += g_Spart[SP(b, jj, p, c, dl)];
    clf[i] = s / (float)NT;
  }
  __syncthreads();
  int lane = tid & 63;
  if (tid < 64) {  // c2 = ||cent||^2, fixed deterministic order
    float q0 = 0.f, q1 = 0.f;
    for (int d = lane; d < ND; d += 64) {
      float a = clf[d], e = clf[ND + d];
      q0 += a * a; q1 += e * e;
    }
    WREDUCE2(q0, q1)
    if (lane == 0) { c2s[0] = q0; c2s[1] = q1; }
  }
  __syncthreads();
  int t = blk * 256 + tid;
  if (t >= NT) return;
  size_t f = (size_t)b * NT + t;
  float g00 = 0.f, g01 = 0.f, g10 = 0.f, g11 = 0.f;
  for (int jj = 0; jj < DS; ++jj) {  // j-ascending fixed order
    float4 p = g_pdot[(size_t)(b * DS + jj) * NT + t];
    g00 += p.x; g01 += p.y; g10 += p.z; g11 += p.w;
  }
  float4 nf = g_nfin[f];
  float a00 = nf.x, a11 = nf.y, asum = nf.z;
  unsigned char st_old = (unsigned char)(g_states[f] & 3);
  float x2_0, x2_1, d00, d01, d10, d11;
  switch (st_old) {
    case 0: x2_0 = a00;  x2_1 = a11;  d00 = g00;       d01 = g01;       d10 = g10;       d11 = g11;       break;
    case 1: x2_0 = a11;  x2_1 = a00;  d00 = g10;       d01 = g11;       d10 = g00;       d11 = g01;       break;
    case 2: x2_0 = asum; x2_1 = 0.f;  d00 = g00 + g10; d01 = g01 + g11; d10 = 0.f;       d11 = 0.f;       break;
    default: x2_0 = 0.f; x2_1 = asum; d00 = 0.f;       d01 = 0.f;       d10 = g00 + g10; d11 = g01 + g11; break;
  }
  float c2_0 = c2s[0], c2_1 = c2s[1];
  float dist00 = (x2_0 + c2_0) - 2.f * d00;
  float dist01 = (x2_0 + c2_1) - 2.f * d01;
  float dist10 = (x2_1 + c2_0) - 2.f * d10;
  float dist11 = (x2_1 + c2_1) - 2.f * d11;
  int i0 = (dist00 <= dist01) ? 0 : 1;   // argmin tie -> 0 (np first-min)
  int i1 = (dist10 <= dist11) ? 0 : 1;
  unsigned char st_new;
  if (i0 == 0 && i1 == 0) st_new = 2;
  else if (i0 == 1 && i1 == 1) st_new = 3;
  else if (i0 == 0) st_new = st_old;
  else st_new = (unsigned char)(st_old ^ 1);
  g_states[f] = st_new;
  if (st_new != st_old) {                 // benign same-value races
    g_changed[iter + 1] = 1;
    int tcc = t / FPC;
    int w = (t - tcc * FPC) >> 8;         // 256-frame wave-chunk within t-chunk
    g_chflag[(size_t)(iter + 1) * NB * NWCH + b * NWCH + tcc * 4 + w] = 1;
  }
}

// ---- C: cluster sub-partials; each wave skips if its 256 frames are clean ----
// Barrier-free, LDS-free (lane-keep reduction).
__global__ __launch_bounds__(256) void csum_kernel(const float* __restrict__ in, int iter) {
  if (g_changed[iter + 1] == 0) return;  // nothing changed anywhere
  int j = blockIdx.x, tc = blockIdx.y, b = blockIdx.z, tid = threadIdx.x;
  int wave = tid >> 6, lane = tid & 63;
  int p = tc * 4 + wave;
  if (g_chflag[(size_t)(iter + 1) * NB * NWCH + b * NWCH + p] == 0)
    return;  // wave-uniform: this 256-frame chunk unchanged, partial still valid
  bool act = tid < APT;
  int t0 = tc * FPC + tid * FPT;
  int t0c = act ? t0 : 0;
  float msk = act ? 1.f : 0.f;
  uchar4 st = *(const uchar4*)&g_states[(size_t)b * NT + t0c];
  bool w00, w10, w01, w11, w02, w12, w03, w13;
  MKW(st.x, w00, w10); MKW(st.y, w01, w11); MKW(st.z, w02, w12); MKW(st.w, w03, w13);
  const float* base0 = in + ((size_t)(b * 2 + 0) * ND) * NT;
  const float* base1 = in + ((size_t)(b * 2 + 1) * ND) * NT;
  float r0 = 0.f, r1 = 0.f;   // lane-keep: dim sums for dl == lane
#pragma unroll 2
  for (int dl = 0; dl < DCH; ++dl) {
    int d = j * DCH + dl;
    float4 v0 = ld4(base0 + (size_t)d * NT + t0c);
    float4 v1 = ld4(base1 + (size_t)d * NT + t0c);
    v0.x *= msk; v0.y *= msk; v0.z *= msk; v0.w *= msk;
    v1.x *= msk; v1.y *= msk; v1.z *= msk; v1.w *= msk;
    float p0x = (w00 ? v0.x : 0.f) + (w10 ? v1.x : 0.f);
    float p1x = (w00 ? 0.f : v0.x) + (w10 ? 0.f : v1.x);
    float p0y = (w01 ? v0.y : 0.f) + (w11 ? v1.y : 0.f);
    float p1y = (w01 ? 0.f : v0.y) + (w11 ? 0.f : v1.y);
    float p0z = (w02 ? v0.z : 0.f) + (w12 ? v1.z : 0.f);
    float p1z = (w02 ? 0.f : v0.z) + (w12 ? 0.f : v1.z);
    float p0w = (w03 ? v0.w : 0.f) + (w13 ? v1.w : 0.f);
    float p1w = (w03 ? 0.f : v0.w) + (w13 ? 0.f : v1.w);
    float a0 = (p0x + p0y) + (p0z + p0w);
    float a1 = (p1x + p1y) + (p1z + p1w);
    WREDUCE2(a0, a1)
    if (lane == dl) { r0 = a0; r1 = a1; }
  }
  g_Spart[SP(b, j, p, 0, lane)] = r0;
  g_Spart[SP(b, j, p, 1, lane)] = r1;
}

// ---- output: exact select/add of original vectors per final state ----
__global__ __launch_bounds__(256) void output_kernel(const float* __restrict__ in,
                                                     float* __restrict__ out) {
  int j = blockIdx.x, tc = blockIdx.y, b = blockIdx.z, tid = threadIdx.x;
  if (tid >= APT) return;
  int t0 = tc * FPC + tid * FPT;
  uchar4 st = *(const uchar4*)&g_states[(size_t)b * NT + t0];
  bool w00, w10, w01, w11, w02, w12, w03, w13;
  MKW(st.x, w00, w10); MKW(st.y, w01, w11); MKW(st.z, w02, w12); MKW(st.w, w03, w13);
  const float* b0 = in + ((size_t)(b * 2 + 0) * ND) * NT;
  const float* b1 = in + ((size_t)(b * 2 + 1) * ND) * NT;
  float* o0 = out + ((size_t)(b * 2 + 0) * ND) * NT;
  float* o1 = out + ((size_t)(b * 2 + 1) * ND) * NT;
#pragma unroll 2
  for (int dl = 0; dl < DCH; ++dl) {
    int d = j * DCH + dl;
    float4 v0 = ld4(b0 + (size_t)d * NT + t0);
    float4 v1 = ld4(b1 + (size_t)d * NT + t0);
    float4 a0, a1;
    a0.x = (w00 ? v0.x : 0.f) + (w10 ? v1.x : 0.f);
    a1.x = (w00 ? 0.f : v0.x) + (w10 ? 0.f : v1.x);
    a0.y = (w01 ? v0.y : 0.f) + (w11 ? v1.y : 0.f);
    a1.y = (w01 ? 0.f : v0.y) + (w11 ? 0.f : v1.y);
    a0.z = (w02 ? v0.z : 0.f) + (w12 ? v1.z : 0.f);
    a1.z = (w02 ? 0.f : v0.z) + (w12 ? 0.f : v1.z);
    a0.w = (w03 ? v0.w : 0.f) + (w13 ? v1.w : 0.f);
    a1.w = (w03 ? 0.f : v0.w) + (w13 ? 0.f : v1.w);
    *(float4*)(o0 + (size_t)d * NT + t0) = a0;
    *(float4*)(o1 + (size_t)d * NT + t0) = a1;
  }
}

extern "C" void kernel_launch(void* const* d_in, const int* in_sizes, int n_in,
                              void* d_out, int out_size, void* d_ws, size_t ws_size,
                              hipStream_t stream) {
  const float* in = (const float*)d_in[0];
  float* out = (float*)d_out;
  (void)d_ws; (void)ws_size; (void)in_sizes; (void)n_in; (void)out_size;

  dim3 g3(DS, TCH, NB), b256(256);
  init_kernel<<<g3, b256, 0, stream>>>(in);
  init2_kernel<<<dim3(63, NB), b256, 0, stream>>>();
  for (int i = 0; i < NITERS; ++i) {
    dots_kernel<<<g3, b256, 0, stream>>>(in, i);
    upd_kernel<<<dim3(63, NB), b256, 0, stream>>>(i);
    if (i < NITERS - 1) csum_kernel<<<g3, b256, 0, stream>>>(in, i);
  }
  output_kernel<<<g3, b256, 0, stream>>>(in, out);
}